// Round 14
// baseline (228.066 us; speedup 1.0000x reference)
//
#include <hip/hip_runtime.h>
#include <stdint.h>

typedef int v4i __attribute__((ext_vector_type(4)));

#define NROWS 8192
#define DIM   1024
#define BK    128
#define NKT   (DIM / BK)   // 8
#define MARGIN 0.3f
#define QSCALE 22.0f                     // int8 quant scale; max|x|~5.4 for N(0,1)
#define QINV   (1.0f / (QSCALE * QSCALE))

// fp32 [8192*1024] -> int8 symmetric quant (q = rint(x*22), clamp +-127).
// rms quant error 0.013 < fp8-e4m3's ~0.03 (both passed absmax 0.0).
// Also zeroes the scalar output.  (R17/R22-verified)
__global__ __launch_bounds__(256) void cvt_f32_i8(const float* __restrict__ in,
                                                  uint8_t* __restrict__ out,
                                                  float* __restrict__ loss) {
  if (blockIdx.x == 0 && threadIdx.x == 0) loss[0] = 0.0f;
  size_t i = ((size_t)blockIdx.x * 256 + threadIdx.x) * 16;
#define Q1(x_) (((int)rintf(fminf(fmaxf((x_) * QSCALE, -127.f), 127.f))) & 255)
#define Q4(v_) ((unsigned)(Q1(v_.x) | (Q1(v_.y) << 8) | (Q1(v_.z) << 16) | (Q1(v_.w) << 24)))
  float4 v0 = *(const float4*)(in + i);
  float4 v1 = *(const float4*)(in + i + 4);
  float4 v2 = *(const float4*)(in + i + 8);
  float4 v3 = *(const float4*)(in + i + 12);
  uint4 p;
  p.x = Q4(v0); p.y = Q4(v1); p.z = Q4(v2); p.w = Q4(v3);
  *(uint4*)(out + i) = p;
#undef Q1
#undef Q4
}

// One block = one 128x128 tile of sim = A*A^T (upper triangle, bi<=bj).
// R23: BARRIER-FREE direct-from-L2 Gram.  R22's decisive result: halving
// MFMA work (MfmaUtil 50->24.6) left the wall bit-flat (55.4 vs 55.5us) ->
// the limiter is the per-K-tile synchronized LDS round-trip (ds_read ->
// lgkm -> barrier -> ... -> vmcnt -> barrier, 8x/block), not any pipe.
// The i8 matrix is 8 MB and PROVEN L2-resident (FETCH 20 MB, super-tiled
// ~4MB/XCD working set since R19).  Per the guide's "don't stage what L2
// fits" lesson (m169, +26%): read each MFMA operand DIRECTLY from global
// as one dwordx4 L2 hit (~200cy, hidden by 12 waves/CU TLP -- no barrier
// couples waves anymore).  Cost: each byte read 2x/block from L2 -> ~1.06
// GB total ~ 31us at 4.3 TB/s/XCD; i8 pipe floor 17.7us; these overlap.
// LDS shrinks to tRow/tCol/wsum; ONE barrier per block.  No XOR swizzle
// (no banks); lane map: A row m0+mi*16+fr, bytes kt*128 + h*16 (+64 for
// the second k-half) -- identical for A and B so the k-order cancels in
// the Gram product (sigma-cancellation, verified absmax 0.0 R17/R20/R22).
// 8 per-lane base pointers; kt*128 <= 960 folds into the 13-bit imm.
__global__ __launch_bounds__(256, 3) void gram_loss(const uint8_t* __restrict__ A8,
                                                    const int* __restrict__ targets,
                                                    float* __restrict__ out) {
  __shared__ int tRow[128];
  __shared__ int tCol[128];
  __shared__ float wsum[4];

  // ---- super-tiled upper-tri block mapping (R19-verified) ----
  const int pos = (blockIdx.x & 7) * 260 + (blockIdx.x >> 3);   // 2080 = 8*260
  int q = 0, pre = 0;
  if (pos >= 136)  { q = 1; pre = 136; }
  if (pos >= 392)  { q = 2; pre = 392; }
  if (pos >= 648)  { q = 3; pre = 648; }
  if (pos >= 904)  { q = 4; pre = 904; }
  if (pos >= 1040) { q = 5; pre = 1040; }
  if (pos >= 1296) { q = 6; pre = 1296; }
  if (pos >= 1552) { q = 7; pre = 1552; }
  if (pos >= 1688) { q = 8; pre = 1688; }
  if (pos >= 1944) { q = 9; pre = 1944; }
  const int r  = pos - pre;
  const int Si = (q >= 4) + (q >= 7) + (q >= 9);            // super-row
  const int Sj = Si + (q - (Si * 4 - (Si * (Si - 1)) / 2)); // super-col
  int li, lj;
  if (Si == Sj) {
    li = (r>=16)+(r>=31)+(r>=45)+(r>=58)+(r>=70)+(r>=81)+(r>=91)+(r>=100)
       + (r>=108)+(r>=115)+(r>=121)+(r>=126)+(r>=130)+(r>=133)+(r>=135);
    lj = li + (r - (li * (33 - li)) / 2);
  } else {
    li = r >> 4;
    lj = r & 15;
  }
  const int bi = Si * 16 + li;
  const int bj = Sj * 16 + lj;

  const int iBase = bi * 128;
  const int jBase = bj * 128;

  const int tid  = threadIdx.x;
  const int wave = tid >> 6;
  const int lane = tid & 63;

  if (tid < 128) tRow[tid] = targets[iBase + tid];
  else           tCol[tid - 128] = targets[jBase + tid - 128];
  __syncthreads();   // the ONLY block-wide barrier (tRow/tCol visible)

  const int m0 = (wave >> 1) * 64;
  const int n0 = (wave & 1) * 64;
  const int fr = lane & 15;    // row within 16-row fragment block
  const int h  = lane >> 4;    // 0..3: k-subgroup (16B) within a 64-k step

  // per-lane fragment base pointers (k-offsets fold into load immediates)
  const uint8_t* pA0 = A8 + (size_t)(iBase + m0 +  0 + fr) * DIM + h * 16;
  const uint8_t* pA1 = A8 + (size_t)(iBase + m0 + 16 + fr) * DIM + h * 16;
  const uint8_t* pA2 = A8 + (size_t)(iBase + m0 + 32 + fr) * DIM + h * 16;
  const uint8_t* pA3 = A8 + (size_t)(iBase + m0 + 48 + fr) * DIM + h * 16;
  const uint8_t* pB0 = A8 + (size_t)(jBase + n0 +  0 + fr) * DIM + h * 16;
  const uint8_t* pB1 = A8 + (size_t)(jBase + n0 + 16 + fr) * DIM + h * 16;
  const uint8_t* pB2 = A8 + (size_t)(jBase + n0 + 32 + fr) * DIM + h * 16;
  const uint8_t* pB3 = A8 + (size_t)(jBase + n0 + 48 + fr) * DIM + h * 16;

  v4i acc[4][4] = {};

  for (int kt = 0; kt < NKT; ++kt) {
    const int kO = kt * BK;          // 0..896: folds into 13-bit imm offset
    v4i a0[4], a1[4], b0[4], b1[4];
    a0[0] = *(const v4i*)(pA0 + kO);      a1[0] = *(const v4i*)(pA0 + kO + 64);
    a0[1] = *(const v4i*)(pA1 + kO);      a1[1] = *(const v4i*)(pA1 + kO + 64);
    a0[2] = *(const v4i*)(pA2 + kO);      a1[2] = *(const v4i*)(pA2 + kO + 64);
    a0[3] = *(const v4i*)(pA3 + kO);      a1[3] = *(const v4i*)(pA3 + kO + 64);
    b0[0] = *(const v4i*)(pB0 + kO);      b1[0] = *(const v4i*)(pB0 + kO + 64);
    b0[1] = *(const v4i*)(pB1 + kO);      b1[1] = *(const v4i*)(pB1 + kO + 64);
    b0[2] = *(const v4i*)(pB2 + kO);      b1[2] = *(const v4i*)(pB2 + kO + 64);
    b0[3] = *(const v4i*)(pB3 + kO);      b1[3] = *(const v4i*)(pB3 + kO + 64);
#pragma unroll
    for (int mi = 0; mi < 4; ++mi)
#pragma unroll
      for (int ni = 0; ni < 4; ++ni) {
        acc[mi][ni] = __builtin_amdgcn_mfma_i32_16x16x64_i8(
            a0[mi], b0[ni], acc[mi][ni], 0, 0, 0);
        acc[mi][ni] = __builtin_amdgcn_mfma_i32_16x16x64_i8(
            a1[mi], b1[ni], acc[mi][ni], 0, 0, 0);
      }
  }

  // epilogue: C/D layout col = lane&15, row = (lane>>4)*4 + reg (dtype-indep)
  const int col = lane & 15;
  const int rquad = (lane >> 4) * 4;
  float lsum = 0.0f;
#pragma unroll
  for (int ni = 0; ni < 4; ++ni) {
    const int tj = tCol[n0 + ni * 16 + col];
#pragma unroll
    for (int mi = 0; mi < 4; ++mi) {
#pragma unroll
      for (int r2 = 0; r2 < 4; ++r2) {
        float s = (float)acc[mi][ni][r2] * QINV;   // dequantized sim
        int ti = tRow[m0 + mi * 16 + rquad + r2];
        lsum += (ti == tj) ? (s < 1.0f ? 1.0f - s : 0.0f)
                           : (s > MARGIN ? s : 0.0f);
      }
    }
  }
  if (bi != bj) lsum *= 2.0f;  // symmetric half counted twice

#pragma unroll
  for (int off = 32; off > 0; off >>= 1) lsum += __shfl_down(lsum, off, 64);
  if (lane == 0) wsum[wave] = lsum;
  __syncthreads();
  if (tid == 0)
    atomicAdd(out, (wsum[0] + wsum[1] + wsum[2] + wsum[3]) * (1.0f / (float)NROWS));
}

extern "C" void kernel_launch(void* const* d_in, const int* in_sizes, int n_in,
                              void* d_out, int out_size, void* d_ws, size_t ws_size,
                              hipStream_t stream) {
  const float* x = (const float*)d_in[0];
  const int* targets = (const int*)d_in[1];
  float* out = (float*)d_out;
  uint8_t* x8 = (uint8_t*)d_ws;  // 8192*1024 = 8 MiB scratch

  cvt_f32_i8<<<2048, 256, 0, stream>>>(x, x8, out);   // 8388608 = 2048*256*16
  gram_loss<<<2080, 256, 0, stream>>>(x8, targets, out);  // 64*65/2 upper-tri blocks
}

// Round 15
// 137.077 us; speedup vs baseline: 1.6638x; 1.6638x over previous
//
#include <hip/hip_runtime.h>
#include <stdint.h>

typedef int v4i __attribute__((ext_vector_type(4)));

#define NROWS 8192
#define DIM   1024
#define BK    128
#define NKT   (DIM / BK)   // 8
#define MARGIN 0.3f
#define QSCALE 22.0f                     // int8 quant scale; max|x|~5.4 for N(0,1)
#define QINV   (1.0f / (QSCALE * QSCALE))

// async global->LDS, 16B per lane; LDS dest = wave-uniform base + lane*16
#define GLOAD_LDS16(gp, lp)                                                    \
  __builtin_amdgcn_global_load_lds(                                            \
      (const __attribute__((address_space(1))) void*)(gp),                     \
      (__attribute__((address_space(3))) void*)(lp), 16, 0, 0)

// fp32 [8192*1024] -> int8 symmetric quant (q = rint(x*22), clamp +-127).
// rms quant error 0.013 < fp8-e4m3's ~0.03 (both passed absmax 0.0).
// Also zeroes the scalar output.  (R17/R22-verified)
__global__ __launch_bounds__(256) void cvt_f32_i8(const float* __restrict__ in,
                                                  uint8_t* __restrict__ out,
                                                  float* __restrict__ loss) {
  if (blockIdx.x == 0 && threadIdx.x == 0) loss[0] = 0.0f;
  size_t i = ((size_t)blockIdx.x * 256 + threadIdx.x) * 16;
#define Q1(x_) (((int)rintf(fminf(fmaxf((x_) * QSCALE, -127.f), 127.f))) & 255)
#define Q4(v_) ((unsigned)(Q1(v_.x) | (Q1(v_.y) << 8) | (Q1(v_.z) << 16) | (Q1(v_.w) << 24)))
  float4 v0 = *(const float4*)(in + i);
  float4 v1 = *(const float4*)(in + i + 4);
  float4 v2 = *(const float4*)(in + i + 8);
  float4 v3 = *(const float4*)(in + i + 12);
  uint4 p;
  p.x = Q4(v0); p.y = Q4(v1); p.z = Q4(v2); p.w = Q4(v3);
  *(uint4*)(out + i) = p;
#undef Q1
#undef Q4
}

// One block = one 128x128 tile of sim = A*A^T (upper triangle, bi<=bj).
// R24: WAVE-PRIVATE LDS staging, ZERO barriers in the K-loop.
// Evidence trail: R20(57us)/R21(55.5)/R22(55.4) are bit-flat across 2x MFMA
// work -> neither pipe binds.  Per CU per K-tile window (~2050cy), resident
// blocks demand ~2300cy of the LDS read pipe (64 ds_read_b128 x ~12cy x 3
// blocks) AND the block-wide barriers phase-align all blocks: read bursts
// collide, LDS saturates in bursts, idles during MFMA phases (convoy).
// R23 (drop LDS entirely, direct-L2) failed 3x: scattered 16B loads swamp
// the request path; contiguous 1KB gload_lds staging was doing real work.
// Fix: each wave owns a PRIVATE 16KB LDS region (its 64 A-rows + 64 B-rows;
// 64KB/block), K-loop fully wave-local:
//   reads(16 b128)->lgkmcnt(0)->STAGE(kt+1,16 gloads)->MFMA->vmcnt(0)
// No s_barrier (regions disjoint; per-wave vmcnt/lgkmcnt order everything).
// Waves drift apart -> LDS/VMEM demand spreads instead of bursting.
// Cost: rows staged 2x/block (L2 traffic 0.53->1.06GB ~ 31us of L2 service,
// overlapped) and 8 waves/CU instead of 12 (but no sibling waits).
// i8 kept (653cy matrix-pipe per wave per K-tile = half of fp8; matters
// once the convoy is gone).  Swizzle/mapping/epilogue: R22-identical.
__global__ __launch_bounds__(256, 2) void gram_loss(const uint8_t* __restrict__ A8,
                                                    const int* __restrict__ targets,
                                                    float* __restrict__ out) {
  __shared__ uint8_t Ls[4][2][64 * 128];   // [wave][A|B][64 rows x 128B] = 64 KB
  __shared__ int tRow[128];
  __shared__ int tCol[128];
  __shared__ float wsum[4];

  // ---- super-tiled upper-tri block mapping (R19-verified) ----
  const int pos = (blockIdx.x & 7) * 260 + (blockIdx.x >> 3);   // 2080 = 8*260
  int q = 0, pre = 0;
  if (pos >= 136)  { q = 1; pre = 136; }
  if (pos >= 392)  { q = 2; pre = 392; }
  if (pos >= 648)  { q = 3; pre = 648; }
  if (pos >= 904)  { q = 4; pre = 904; }
  if (pos >= 1040) { q = 5; pre = 1040; }
  if (pos >= 1296) { q = 6; pre = 1296; }
  if (pos >= 1552) { q = 7; pre = 1552; }
  if (pos >= 1688) { q = 8; pre = 1688; }
  if (pos >= 1944) { q = 9; pre = 1944; }
  const int r  = pos - pre;
  const int Si = (q >= 4) + (q >= 7) + (q >= 9);            // super-row
  const int Sj = Si + (q - (Si * 4 - (Si * (Si - 1)) / 2)); // super-col
  int li, lj;
  if (Si == Sj) {
    li = (r>=16)+(r>=31)+(r>=45)+(r>=58)+(r>=70)+(r>=81)+(r>=91)+(r>=100)
       + (r>=108)+(r>=115)+(r>=121)+(r>=126)+(r>=130)+(r>=133)+(r>=135);
    lj = li + (r - (li * (33 - li)) / 2);
  } else {
    li = r >> 4;
    lj = r & 15;
  }
  const int bi = Si * 16 + li;
  const int bj = Sj * 16 + lj;

  const int iBase = bi * 128;
  const int jBase = bj * 128;

  const int tid  = threadIdx.x;
  const int wave = tid >> 6;
  const int lane = tid & 63;

  if (tid < 128) tRow[tid] = targets[iBase + tid];
  else           tCol[tid - 128] = targets[jBase + tid - 128];
  __syncthreads();   // tRow/tCol visible (only block-wide sync besides wsum)

  const int m0 = (wave >> 1) * 64;   // wave's 64x64 output tile
  const int n0 = (wave & 1) * 64;

  // wave-private staging: this wave stages A rows [m0,m0+64) and B rows
  // [n0,n0+64) into its own region.  One gload = 8 rows x 128B; lane ->
  // row lane>>3, swizzled source col-group (lane&7)^(lane>>3).
  const int lrow = lane >> 3;                 // 0..7 == row&7
  const int cg   = (lane & 7) ^ lrow;         // swizzled source col-group
  const uint8_t* gA = A8 + (size_t)(iBase + m0 + lrow) * DIM + cg * 16;
  const uint8_t* gB = A8 + (size_t)(jBase + n0 + lrow) * DIM + cg * 16;
  uint8_t* lA = &Ls[wave][0][0];
  uint8_t* lB = &Ls[wave][1][0];

  const int fr = lane & 15;    // row within 16-row fragment block
  const int h  = lane >> 4;    // 0..3: this lane's k-subgroup
  const int r7 = fr & 7;       // swizzle key (rows 16-aligned per fragment)
  const int s0 = ((h    ) ^ r7) * 16;   // slot byte-offset: global group h
  const int s1 = ((h + 4) ^ r7) * 16;   // slot byte-offset: global group h+4

  v4i acc[4][4] = {};

#define STAGE(kt_)                                                             \
  { const int kO_ = (kt_) * BK;                                                \
    _Pragma("unroll")                                                          \
    for (int l = 0; l < 8; ++l)                                                \
      GLOAD_LDS16(gA + (size_t)(l * 8) * DIM + kO_, lA + l * 8 * 128);         \
    _Pragma("unroll")                                                          \
    for (int l = 0; l < 8; ++l)                                                \
      GLOAD_LDS16(gB + (size_t)(l * 8) * DIM + kO_, lB + l * 8 * 128); }

  // prologue: tile 0 staged and landed (wave-local)
  STAGE(0);
  asm volatile("s_waitcnt vmcnt(0)" ::: "memory");

  for (int kt = 0; kt < NKT; ++kt) {
    // 1) read tile kt's fragments (16 x b128 = 64 VGPR); buffer-local rows
    v4i a0[4], b0[4], a1[4], b1[4];
#pragma unroll
    for (int mi = 0; mi < 4; ++mi)
      a0[mi] = *(const v4i*)&lA[(mi * 16 + fr) * 128 + s0];
#pragma unroll
    for (int ni = 0; ni < 4; ++ni)
      b0[ni] = *(const v4i*)&lB[(ni * 16 + fr) * 128 + s0];
#pragma unroll
    for (int mi = 0; mi < 4; ++mi)
      a1[mi] = *(const v4i*)&lA[(mi * 16 + fr) * 128 + s1];
#pragma unroll
    for (int ni = 0; ni < 4; ++ni)
      b1[ni] = *(const v4i*)&lB[(ni * 16 + fr) * 128 + s1];
    // 2) my reads retired -> my buffer is overwritable (wave-local)
    asm volatile("s_waitcnt lgkmcnt(0)" ::: "memory");
    // 3) stage tile kt+1 into my own region; loads stay in flight
    if (kt + 1 < NKT) STAGE(kt + 1);
    __builtin_amdgcn_sched_barrier(0);   // MFMAs must not hoist above STAGE
    // 4) compute tile kt from registers (covers the staging latency)
#pragma unroll
    for (int mi = 0; mi < 4; ++mi)
#pragma unroll
      for (int ni = 0; ni < 4; ++ni) {
        acc[mi][ni] = __builtin_amdgcn_mfma_i32_16x16x64_i8(
            a0[mi], b0[ni], acc[mi][ni], 0, 0, 0);
        acc[mi][ni] = __builtin_amdgcn_mfma_i32_16x16x64_i8(
            a1[mi], b1[ni], acc[mi][ni], 0, 0, 0);
      }
    __builtin_amdgcn_sched_barrier(0);   // MFMAs must not sink below vmcnt
    // 5) my tile kt+1 landed (wave-local; no s_barrier)
    asm volatile("s_waitcnt vmcnt(0)" ::: "memory");
  }
#undef STAGE

  // epilogue: C/D layout col = lane&15, row = (lane>>4)*4 + reg (dtype-indep)
  const int col = lane & 15;
  const int rquad = (lane >> 4) * 4;
  float lsum = 0.0f;
#pragma unroll
  for (int ni = 0; ni < 4; ++ni) {
    const int tj = tCol[n0 + ni * 16 + col];
#pragma unroll
    for (int mi = 0; mi < 4; ++mi) {
#pragma unroll
      for (int r2 = 0; r2 < 4; ++r2) {
        float s = (float)acc[mi][ni][r2] * QINV;   // dequantized sim
        int ti = tRow[m0 + mi * 16 + rquad + r2];
        lsum += (ti == tj) ? (s < 1.0f ? 1.0f - s : 0.0f)
                           : (s > MARGIN ? s : 0.0f);
      }
    }
  }
  if (bi != bj) lsum *= 2.0f;  // symmetric half counted twice

#pragma unroll
  for (int off = 32; off > 0; off >>= 1) lsum += __shfl_down(lsum, off, 64);
  if (lane == 0) wsum[wave] = lsum;
  __syncthreads();
  if (tid == 0)
    atomicAdd(out, (wsum[0] + wsum[1] + wsum[2] + wsum[3]) * (1.0f / (float)NROWS));
}

extern "C" void kernel_launch(void* const* d_in, const int* in_sizes, int n_in,
                              void* d_out, int out_size, void* d_ws, size_t ws_size,
                              hipStream_t stream) {
  const float* x = (const float*)d_in[0];
  const int* targets = (const int*)d_in[1];
  float* out = (float*)d_out;
  uint8_t* x8 = (uint8_t*)d_ws;  // 8192*1024 = 8 MiB scratch

  cvt_f32_i8<<<2048, 256, 0, stream>>>(x, x8, out);   // 8388608 = 2048*256*16
  gram_loss<<<2080, 256, 0, stream>>>(x8, targets, out);  // 64*65/2 upper-tri blocks
}

// Round 16
// 135.637 us; speedup vs baseline: 1.6814x; 1.0106x over previous
//
#include <hip/hip_runtime.h>
#include <stdint.h>

typedef float f32x4 __attribute__((ext_vector_type(4)));
typedef long  v2l   __attribute__((ext_vector_type(2)));

#define NROWS 8192
#define DIM   1024
#define BK    128
#define NKT   (DIM / BK)   // 8
#define MARGIN 0.3f

// async global->LDS, 16B per lane; LDS dest = wave-uniform base + lane*16
#define GLOAD_LDS16(gp, lp)                                                    \
  __builtin_amdgcn_global_load_lds(                                            \
      (const __attribute__((address_space(1))) void*)(gp),                     \
      (__attribute__((address_space(3))) void*)(lp), 16, 0, 0)

// fp32 [8192*1024] -> fp8 e4m3 (OCP, v_cvt_pk_fp8_f32); 16 elems/thread.
// Also zeroes the scalar output.  (verified correct R6-R8: absmax 0.0)
__global__ __launch_bounds__(256) void cvt_f32_fp8(const float* __restrict__ in,
                                                   uint8_t* __restrict__ out,
                                                   float* __restrict__ loss) {
  if (blockIdx.x == 0 && threadIdx.x == 0) loss[0] = 0.0f;
  size_t i = ((size_t)blockIdx.x * 256 + threadIdx.x) * 16;
  float4 v0 = *(const float4*)(in + i);
  float4 v1 = *(const float4*)(in + i + 4);
  float4 v2 = *(const float4*)(in + i + 8);
  float4 v3 = *(const float4*)(in + i + 12);
  int w0 = 0, w1 = 0, w2 = 0, w3 = 0;
  w0 = __builtin_amdgcn_cvt_pk_fp8_f32(v0.x, v0.y, w0, false);
  w0 = __builtin_amdgcn_cvt_pk_fp8_f32(v0.z, v0.w, w0, true);
  w1 = __builtin_amdgcn_cvt_pk_fp8_f32(v1.x, v1.y, w1, false);
  w1 = __builtin_amdgcn_cvt_pk_fp8_f32(v1.z, v1.w, w1, true);
  w2 = __builtin_amdgcn_cvt_pk_fp8_f32(v2.x, v2.y, w2, false);
  w2 = __builtin_amdgcn_cvt_pk_fp8_f32(v2.z, v2.w, w2, true);
  w3 = __builtin_amdgcn_cvt_pk_fp8_f32(v3.x, v3.y, w3, false);
  w3 = __builtin_amdgcn_cvt_pk_fp8_f32(v3.z, v3.w, w3, true);
  uint4 p; p.x = (unsigned)w0; p.y = (unsigned)w1; p.z = (unsigned)w2; p.w = (unsigned)w3;
  *(uint4*)(out + i) = p;
}

// One block = one 128x128 tile of sim = A*A^T (upper triangle, bi<=bj).
// R25 == R21's overlap at R20's register footprint -> 4 blocks/CU.
// Ledger: wall flat ~55us across 2x MFMA work, conflict-free LDS, 1-deep
// prefetch; moves AGAINST us whenever blocks/CU drops (3blk 55.5 / 2blk
// 67-100 / ~1blk 160).  No pipe saturated (MFMA 62%, LDS-read 37%, VMEM
// 24% of wall) -> residual is barrier-synced latency that TLP absorbs.
// R21 blocks the 4th block: 76 VGPR + 64 AGPR = 140 > 128-per-wave needed
// for 4 waves/SIMD.  Fix: split fragment reads into two k-half phases
// (16 operand VGPRs live per phase, not 64):
//   phase0: read s0-half (8 b128) + 32 MFMA          [no staging here]
//   phase1: read s1-half -> lgkm(0) -> barrier        [LDS dead]
//           STAGE(kt+1) -> 32 MFMA (covers L2 RT) -> vmcnt(0) -> barrier
// Same 2 barriers/K-tile, conflict-free slots, super-tiled map, fp8.
// launch_bounds(256,4): ~64 arch + 64 acc = 128 -> 16 waves/CU.
__global__ __launch_bounds__(256, 4) void gram_loss(const uint8_t* __restrict__ A8,
                                                    const int* __restrict__ targets,
                                                    float* __restrict__ out) {
  __shared__ uint8_t As[128 * 128];   // 16 KB, swizzled [128][8 slots of 16B]
  __shared__ uint8_t Bs[128 * 128];   // 16 KB
  __shared__ int tRow[128];
  __shared__ int tCol[128];
  __shared__ float wsum[4];

  // ---- super-tiled upper-tri block mapping (R19-verified) ----
  const int pos = (blockIdx.x & 7) * 260 + (blockIdx.x >> 3);   // 2080 = 8*260
  int q = 0, pre = 0;
  if (pos >= 136)  { q = 1; pre = 136; }
  if (pos >= 392)  { q = 2; pre = 392; }
  if (pos >= 648)  { q = 3; pre = 648; }
  if (pos >= 904)  { q = 4; pre = 904; }
  if (pos >= 1040) { q = 5; pre = 1040; }
  if (pos >= 1296) { q = 6; pre = 1296; }
  if (pos >= 1552) { q = 7; pre = 1552; }
  if (pos >= 1688) { q = 8; pre = 1688; }
  if (pos >= 1944) { q = 9; pre = 1944; }
  const int r  = pos - pre;
  const int Si = (q >= 4) + (q >= 7) + (q >= 9);            // super-row
  const int Sj = Si + (q - (Si * 4 - (Si * (Si - 1)) / 2)); // super-col
  int li, lj;
  if (Si == Sj) {
    li = (r>=16)+(r>=31)+(r>=45)+(r>=58)+(r>=70)+(r>=81)+(r>=91)+(r>=100)
       + (r>=108)+(r>=115)+(r>=121)+(r>=126)+(r>=130)+(r>=133)+(r>=135);
    lj = li + (r - (li * (33 - li)) / 2);
  } else {
    li = r >> 4;
    lj = r & 15;
  }
  const int bi = Si * 16 + li;
  const int bj = Sj * 16 + lj;

  const int iBase = bi * 128;
  const int jBase = bj * 128;

  const int tid  = threadIdx.x;
  const int wave = tid >> 6;
  const int lane = tid & 63;

  if (tid < 128) tRow[tid] = targets[iBase + tid];
  else           tCol[tid - 128] = targets[jBase + tid - 128];

  // staging: wave w stages rows [w*32, w*32+32) of both tiles, 4 loads each.
  // one load = 64 lanes x 16B = 8 rows x 128B; lane -> row offset lane>>3,
  // SWIZZLED source col-group (lane&7) ^ (lane>>3).
  const int lrow = lane >> 3;                 // 0..7 == row&7
  const int cg   = (lane & 7) ^ lrow;         // swizzled source col-group
  const uint8_t* gA = A8 + (size_t)(iBase + wave * 32 + lrow) * DIM + cg * 16;
  const uint8_t* gB = A8 + (size_t)(jBase + wave * 32 + lrow) * DIM + cg * 16;
  uint8_t* lA = &As[wave * 32 * 128];
  uint8_t* lB = &Bs[wave * 32 * 128];

  const int m0 = (wave >> 1) * 64;
  const int n0 = (wave & 1) * 64;
  const int fr = lane & 15;    // row within 16-block
  const int h  = lane >> 4;    // 0..3: this lane's k-subgroup
  const int r7 = fr & 7;       // swizzle key (rows 16-aligned per fragment)
  const int s0 = ((h    ) ^ r7) * 16;   // slot byte-offset: global group h
  const int s1 = ((h + 4) ^ r7) * 16;   // slot byte-offset: global group h+4

  f32x4 acc[4][4] = {};

#define STAGE(kt_)                                                             \
  { const int kO_ = (kt_) * BK;                                                \
    _Pragma("unroll")                                                          \
    for (int l = 0; l < 4; ++l)                                                \
      GLOAD_LDS16(gA + (size_t)(l * 8) * DIM + kO_, lA + l * 8 * 128);         \
    _Pragma("unroll")                                                          \
    for (int l = 0; l < 4; ++l)                                                \
      GLOAD_LDS16(gB + (size_t)(l * 8) * DIM + kO_, lB + l * 8 * 128); }

  // prologue: tile 0 staged and landed (barrier also covers tRow/tCol)
  STAGE(0);
  asm volatile("s_waitcnt vmcnt(0)" ::: "memory");
  __builtin_amdgcn_s_barrier();

  for (int kt = 0; kt < NKT; ++kt) {
    // phase 0: s0 k-half -- read 8 b128 (16 VGPR) and compute 32 MFMAs
    {
      v2l a[4], b[4];
#pragma unroll
      for (int mi = 0; mi < 4; ++mi)
        a[mi] = *(const v2l*)&As[(m0 + mi * 16 + fr) * 128 + s0];
#pragma unroll
      for (int ni = 0; ni < 4; ++ni)
        b[ni] = *(const v2l*)&Bs[(n0 + ni * 16 + fr) * 128 + s0];
#pragma unroll
      for (int mi = 0; mi < 4; ++mi)
#pragma unroll
        for (int ni = 0; ni < 4; ++ni) {
          acc[mi][ni] = __builtin_amdgcn_mfma_f32_16x16x32_fp8_fp8(
              a[mi].x, b[ni].x, acc[mi][ni], 0, 0, 0);
          acc[mi][ni] = __builtin_amdgcn_mfma_f32_16x16x32_fp8_fp8(
              a[mi].y, b[ni].y, acc[mi][ni], 0, 0, 0);
        }
    }
    // phase 1: s1 k-half -- read, then barrier (LDS dead), stage kt+1,
    // compute while the staging loads are in flight
    {
      v2l a[4], b[4];
#pragma unroll
      for (int mi = 0; mi < 4; ++mi)
        a[mi] = *(const v2l*)&As[(m0 + mi * 16 + fr) * 128 + s1];
#pragma unroll
      for (int ni = 0; ni < 4; ++ni)
        b[ni] = *(const v2l*)&Bs[(n0 + ni * 16 + fr) * 128 + s1];
      asm volatile("s_waitcnt lgkmcnt(0)" ::: "memory");
      __builtin_amdgcn_s_barrier();
      if (kt + 1 < NKT) STAGE(kt + 1);
      __builtin_amdgcn_sched_barrier(0);   // MFMAs must not hoist above STAGE
#pragma unroll
      for (int mi = 0; mi < 4; ++mi)
#pragma unroll
        for (int ni = 0; ni < 4; ++ni) {
          acc[mi][ni] = __builtin_amdgcn_mfma_f32_16x16x32_fp8_fp8(
              a[mi].x, b[ni].x, acc[mi][ni], 0, 0, 0);
          acc[mi][ni] = __builtin_amdgcn_mfma_f32_16x16x32_fp8_fp8(
              a[mi].y, b[ni].y, acc[mi][ni], 0, 0, 0);
        }
      __builtin_amdgcn_sched_barrier(0);   // MFMAs must not sink below vmcnt
      asm volatile("s_waitcnt vmcnt(0)" ::: "memory");
      __builtin_amdgcn_s_barrier();
    }
  }
#undef STAGE

  // epilogue: C/D layout col = lane&15, row = (lane>>4)*4 + reg (dtype-indep)
  const int col = lane & 15;
  const int rquad = (lane >> 4) * 4;
  float lsum = 0.0f;
#pragma unroll
  for (int ni = 0; ni < 4; ++ni) {
    const int tj = tCol[n0 + ni * 16 + col];
#pragma unroll
    for (int mi = 0; mi < 4; ++mi) {
#pragma unroll
      for (int r2 = 0; r2 < 4; ++r2) {
        float s = acc[mi][ni][r2];
        int ti = tRow[m0 + mi * 16 + rquad + r2];
        lsum += (ti == tj) ? (s < 1.0f ? 1.0f - s : 0.0f)
                           : (s > MARGIN ? s : 0.0f);
      }
    }
  }
  if (bi != bj) lsum *= 2.0f;  // symmetric half counted twice

#pragma unroll
  for (int off = 32; off > 0; off >>= 1) lsum += __shfl_down(lsum, off, 64);
  if (lane == 0) wsum[wave] = lsum;
  __syncthreads();
  if (tid == 0)
    atomicAdd(out, (wsum[0] + wsum[1] + wsum[2] + wsum[3]) * (1.0f / (float)NROWS));
}

extern "C" void kernel_launch(void* const* d_in, const int* in_sizes, int n_in,
                              void* d_out, int out_size, void* d_ws, size_t ws_size,
                              hipStream_t stream) {
  const float* x = (const float*)d_in[0];
  const int* targets = (const int*)d_in[1];
  float* out = (float*)d_out;
  uint8_t* x8 = (uint8_t*)d_ws;  // 8192*1024 = 8 MiB scratch

  cvt_f32_fp8<<<2048, 256, 0, stream>>>(x, x8, out);   // 8388608 = 2048*256*16
  gram_loss<<<2080, 256, 0, stream>>>(x8, targets, out);  // 64*65/2 upper-tri blocks
}

// Round 17
// 120.294 us; speedup vs baseline: 1.8959x; 1.1275x over previous
//
#include <hip/hip_runtime.h>
#include <stdint.h>

typedef float f32x4 __attribute__((ext_vector_type(4)));
typedef long  v2l   __attribute__((ext_vector_type(2)));

#define NROWS 8192
#define DIM   1024
#define BK    128
#define NKT   (DIM / BK)   // 8
#define MARGIN 0.3f

// async global->LDS, 16B per lane; LDS dest = wave-uniform base + lane*16
#define GLOAD_LDS16(gp, lp)                                                    \
  __builtin_amdgcn_global_load_lds(                                            \
      (const __attribute__((address_space(1))) void*)(gp),                     \
      (__attribute__((address_space(3))) void*)(lp), 16, 0, 0)

// fp32 [8192*1024] -> fp8 e4m3 (OCP, v_cvt_pk_fp8_f32); 16 elems/thread.
// Also zeroes the scalar output.  (verified correct R6-R8: absmax 0.0)
__global__ __launch_bounds__(256) void cvt_f32_fp8(const float* __restrict__ in,
                                                   uint8_t* __restrict__ out,
                                                   float* __restrict__ loss) {
  if (blockIdx.x == 0 && threadIdx.x == 0) loss[0] = 0.0f;
  size_t i = ((size_t)blockIdx.x * 256 + threadIdx.x) * 16;
  float4 v0 = *(const float4*)(in + i);
  float4 v1 = *(const float4*)(in + i + 4);
  float4 v2 = *(const float4*)(in + i + 8);
  float4 v3 = *(const float4*)(in + i + 12);
  int w0 = 0, w1 = 0, w2 = 0, w3 = 0;
  w0 = __builtin_amdgcn_cvt_pk_fp8_f32(v0.x, v0.y, w0, false);
  w0 = __builtin_amdgcn_cvt_pk_fp8_f32(v0.z, v0.w, w0, true);
  w1 = __builtin_amdgcn_cvt_pk_fp8_f32(v1.x, v1.y, w1, false);
  w1 = __builtin_amdgcn_cvt_pk_fp8_f32(v1.z, v1.w, w1, true);
  w2 = __builtin_amdgcn_cvt_pk_fp8_f32(v2.x, v2.y, w2, false);
  w2 = __builtin_amdgcn_cvt_pk_fp8_f32(v2.z, v2.w, w2, true);
  w3 = __builtin_amdgcn_cvt_pk_fp8_f32(v3.x, v3.y, w3, false);
  w3 = __builtin_amdgcn_cvt_pk_fp8_f32(v3.z, v3.w, w3, true);
  uint4 p; p.x = (unsigned)w0; p.y = (unsigned)w1; p.z = (unsigned)w2; p.w = (unsigned)w3;
  *(uint4*)(out + i) = p;
}

// One block = one 128x128 tile of sim = A*A^T (upper triangle, bi<=bj).
// R26 == R21 verbatim (session scored-best: 124.1 us, absmax 0.0).
// Structure: conflict-free b128 paired-k fragment reads (bank conflicts
// 8.5M -> 0, R20) + super-tiled L2-resident block mapping (FETCH 62 -> 20
// MB, R19) + one-ahead staging overlap in a single LDS buffer (R18/R21):
//   read 16 b128 frags -> 64 VGPR ; lgkmcnt(0) ; barrier   [LDS dead]
//   STAGE(kt+1) into SAME buffer ; sched_barrier(0)        [in flight]
//   64 MFMAs from registers                                 [covers L2 RT]
//   sched_barrier(0) ; vmcnt(0) ; barrier                  [landed]
// Falsified levers (do not revisit): i8 2x-rate MFMA (wall flat, R22);
// occupancy 4 blocks/CU (epilogue spill + L2 thrash, R25); 2 blocks/CU
// dbuf (R16) / wave-private LDS (R24); direct-from-L2 operands (R23,
// 3x regression); MX-scaled fp8 (toolchain spills, R10-R14).
__global__ __launch_bounds__(256, 3) void gram_loss(const uint8_t* __restrict__ A8,
                                                    const int* __restrict__ targets,
                                                    float* __restrict__ out) {
  __shared__ uint8_t As[128 * 128];   // 16 KB, swizzled [128][8 slots of 16B]
  __shared__ uint8_t Bs[128 * 128];   // 16 KB
  __shared__ int tRow[128];
  __shared__ int tCol[128];
  __shared__ float wsum[4];

  // ---- super-tiled upper-tri block mapping (R19-verified) ----
  const int pos = (blockIdx.x & 7) * 260 + (blockIdx.x >> 3);   // 2080 = 8*260
  int q = 0, pre = 0;
  if (pos >= 136)  { q = 1; pre = 136; }
  if (pos >= 392)  { q = 2; pre = 392; }
  if (pos >= 648)  { q = 3; pre = 648; }
  if (pos >= 904)  { q = 4; pre = 904; }
  if (pos >= 1040) { q = 5; pre = 1040; }
  if (pos >= 1296) { q = 6; pre = 1296; }
  if (pos >= 1552) { q = 7; pre = 1552; }
  if (pos >= 1688) { q = 8; pre = 1688; }
  if (pos >= 1944) { q = 9; pre = 1944; }
  const int r  = pos - pre;
  const int Si = (q >= 4) + (q >= 7) + (q >= 9);            // super-row
  const int Sj = Si + (q - (Si * 4 - (Si * (Si - 1)) / 2)); // super-col
  int li, lj;
  if (Si == Sj) {
    li = (r>=16)+(r>=31)+(r>=45)+(r>=58)+(r>=70)+(r>=81)+(r>=91)+(r>=100)
       + (r>=108)+(r>=115)+(r>=121)+(r>=126)+(r>=130)+(r>=133)+(r>=135);
    lj = li + (r - (li * (33 - li)) / 2);
  } else {
    li = r >> 4;
    lj = r & 15;
  }
  const int bi = Si * 16 + li;
  const int bj = Sj * 16 + lj;

  const int iBase = bi * 128;
  const int jBase = bj * 128;

  const int tid  = threadIdx.x;
  const int wave = tid >> 6;
  const int lane = tid & 63;

  if (tid < 128) tRow[tid] = targets[iBase + tid];
  else           tCol[tid - 128] = targets[jBase + tid - 128];

  // staging: wave w stages rows [w*32, w*32+32) of both tiles, 4 loads each.
  // one load = 64 lanes x 16B = 8 rows x 128B; lane -> row offset lane>>3,
  // SWIZZLED source col-group (lane&7) ^ (lane>>3).
  const int lrow = lane >> 3;                 // 0..7 == row&7
  const int cg   = (lane & 7) ^ lrow;         // swizzled source col-group
  const uint8_t* gA = A8 + (size_t)(iBase + wave * 32 + lrow) * DIM + cg * 16;
  const uint8_t* gB = A8 + (size_t)(jBase + wave * 32 + lrow) * DIM + cg * 16;
  uint8_t* lA = &As[wave * 32 * 128];
  uint8_t* lB = &Bs[wave * 32 * 128];

  const int m0 = (wave >> 1) * 64;
  const int n0 = (wave & 1) * 64;
  const int fr = lane & 15;    // row within 16-block
  const int h  = lane >> 4;    // 0..3: this lane's k-subgroup
  const int r7 = fr & 7;       // swizzle key (rows 16-aligned per fragment)
  const int s0 = ((h    ) ^ r7) * 16;   // slot byte-offset: global group h
  const int s1 = ((h + 4) ^ r7) * 16;   // slot byte-offset: global group h+4

  f32x4 acc[4][4] = {};

#define STAGE(kt_)                                                             \
  { const int kO_ = (kt_) * BK;                                                \
    _Pragma("unroll")                                                          \
    for (int l = 0; l < 4; ++l)                                                \
      GLOAD_LDS16(gA + (size_t)(l * 8) * DIM + kO_, lA + l * 8 * 128);         \
    _Pragma("unroll")                                                          \
    for (int l = 0; l < 4; ++l)                                                \
      GLOAD_LDS16(gB + (size_t)(l * 8) * DIM + kO_, lB + l * 8 * 128); }

  // prologue: tile 0 staged and landed (barrier also covers tRow/tCol)
  STAGE(0);
  asm volatile("s_waitcnt vmcnt(0)" ::: "memory");
  __builtin_amdgcn_s_barrier();

  for (int kt = 0; kt < NKT; ++kt) {
    // 1) read ALL fragments of tile kt into registers (16 x b128 = 64 VGPR)
    v2l a0[4], b0[4], a1[4], b1[4];
#pragma unroll
    for (int mi = 0; mi < 4; ++mi)
      a0[mi] = *(const v2l*)&As[(m0 + mi * 16 + fr) * 128 + s0];
#pragma unroll
    for (int ni = 0; ni < 4; ++ni)
      b0[ni] = *(const v2l*)&Bs[(n0 + ni * 16 + fr) * 128 + s0];
#pragma unroll
    for (int mi = 0; mi < 4; ++mi)
      a1[mi] = *(const v2l*)&As[(m0 + mi * 16 + fr) * 128 + s1];
#pragma unroll
    for (int ni = 0; ni < 4; ++ni)
      b1[ni] = *(const v2l*)&Bs[(n0 + ni * 16 + fr) * 128 + s1];
    // 2) my reads done -> barrier: LDS is dead for everyone
    asm volatile("s_waitcnt lgkmcnt(0)" ::: "memory");
    __builtin_amdgcn_s_barrier();
    // 3) stage tile kt+1 into the same buffer; loads stay in flight
    if (kt + 1 < NKT) STAGE(kt + 1);
    __builtin_amdgcn_sched_barrier(0);   // MFMAs must not hoist above STAGE
    // 4) compute tile kt entirely from registers (covers load latency)
#pragma unroll
    for (int mi = 0; mi < 4; ++mi)
#pragma unroll
      for (int ni = 0; ni < 4; ++ni) {
        acc[mi][ni] = __builtin_amdgcn_mfma_f32_16x16x32_fp8_fp8(
            a0[mi].x, b0[ni].x, acc[mi][ni], 0, 0, 0);
        acc[mi][ni] = __builtin_amdgcn_mfma_f32_16x16x32_fp8_fp8(
            a0[mi].y, b0[ni].y, acc[mi][ni], 0, 0, 0);
        acc[mi][ni] = __builtin_amdgcn_mfma_f32_16x16x32_fp8_fp8(
            a1[mi].x, b1[ni].x, acc[mi][ni], 0, 0, 0);
        acc[mi][ni] = __builtin_amdgcn_mfma_f32_16x16x32_fp8_fp8(
            a1[mi].y, b1[ni].y, acc[mi][ni], 0, 0, 0);
      }
    __builtin_amdgcn_sched_barrier(0);   // MFMAs must not sink below vmcnt
    // 5) tile kt+1 landed for all waves
    asm volatile("s_waitcnt vmcnt(0)" ::: "memory");
    __builtin_amdgcn_s_barrier();
  }
#undef STAGE

  // epilogue: C/D layout col = lane&15, row = (lane>>4)*4 + reg (dtype-indep)
  const int col = lane & 15;
  const int rquad = (lane >> 4) * 4;
  float lsum = 0.0f;
#pragma unroll
  for (int ni = 0; ni < 4; ++ni) {
    const int tj = tCol[n0 + ni * 16 + col];
#pragma unroll
    for (int mi = 0; mi < 4; ++mi) {
#pragma unroll
      for (int r2 = 0; r2 < 4; ++r2) {
        float s = acc[mi][ni][r2];
        int ti = tRow[m0 + mi * 16 + rquad + r2];
        lsum += (ti == tj) ? (s < 1.0f ? 1.0f - s : 0.0f)
                           : (s > MARGIN ? s : 0.0f);
      }
    }
  }
  if (bi != bj) lsum *= 2.0f;  // symmetric half counted twice

#pragma unroll
  for (int off = 32; off > 0; off >>= 1) lsum += __shfl_down(lsum, off, 64);
  if (lane == 0) wsum[wave] = lsum;
  __syncthreads();
  if (tid == 0)
    atomicAdd(out, (wsum[0] + wsum[1] + wsum[2] + wsum[3]) * (1.0f / (float)NROWS));
}

extern "C" void kernel_launch(void* const* d_in, const int* in_sizes, int n_in,
                              void* d_out, int out_size, void* d_ws, size_t ws_size,
                              hipStream_t stream) {
  const float* x = (const float*)d_in[0];
  const int* targets = (const int*)d_in[1];
  float* out = (float*)d_out;
  uint8_t* x8 = (uint8_t*)d_ws;  // 8192*1024 = 8 MiB scratch

  cvt_f32_fp8<<<2048, 256, 0, stream>>>(x, x8, out);   // 8388608 = 2048*256*16
  gram_loss<<<2080, 256, 0, stream>>>(x8, targets, out);  // 64*65/2 upper-tri blocks
}